// Round 5
// baseline (277.045 us; speedup 1.0000x reference)
//
#include <hip/hip_runtime.h>
#include <float.h>

// FeatPropagation k=3 NN interpolation, round 9b (R9 + pragma placement fix).
// R8 post-mortem: VGPR=56 -> banks collapsed again; but the real finding is
// cross-round: 4 different point-stream structures all land 146-156us while
// occupancy halved with no dur change -> NOT latency-bound. The "VALUBusy 2x
// inflated" lore (R4) is contradicted (implied busy < computable floor).
// Consistent model: genuinely VALU-bound, dominated by the f64 min/max
// selection network (~8cyc/op quarter-rate): 10 f64 ops/point-pair = ~80 of
// ~110 cyc. R9: (a) selection -> 2-pass f32 filter-refine: pass1 keeps 3
// smallest d2 VALUES (5x f32 minmax), merge -> threshold T; pass2 rescans
// (bit-identical d2) pushing rare d2<=T hits to LDS shortlist; finalize sorts
// <=8 (d2,idx) pairs lexicographically (ties->lower idx, == jax top_k
// stability; exact serial fallback if >8 ties). (b) split select/gather into
// two kernels for per-phase rocprof dur + no barrier convoy.
//
// PROTECTED (absmax 0.015625): d2 computed as (q2+s2) - 2*((qx*sx+qy*sy)+qz*sz)
// with per-op f32 rounding (contract off, no fma, no reassociation) in this
// exact order, in BOTH passes; selection = lexicographic min on (d2, idx);
// weights w_i = (1/(sqrt(max(d2,1e-12))+1e-8)) / sum, same op order as prior
// rounds. Do NOT switch to fma/dx^2 form.

#define QPL   2     // queries per lane
#define QPB   128   // queries per block = 64 * QPL
#define SPLIT 8     // candidate chunks per block == waves per block
#define CAP   8     // shortlist capacity per query
#define KEY_INIT 0x7FEFFFFFFFFFFFFFULL  // > any real packed key (fused path)

typedef float v2f __attribute__((ext_vector_type(2)));

__global__ void pack_pts(const float* __restrict__ xyz,
                         float4* __restrict__ pts, int total) {
    int i = blockIdx.x * blockDim.x + threadIdx.x;
    if (i < total) {
        const float sx = xyz[(size_t)i * 3 + 0];
        const float sy = xyz[(size_t)i * 3 + 1];
        const float sz = xyz[(size_t)i * 3 + 2];
        const float s2 = __fadd_rn(__fadd_rn(__fmul_rn(sx, sx), __fmul_rn(sy, sy)),
                                   __fmul_rn(sz, sz));
        pts[i] = make_float4(sx, sy, sz, s2);
    }
}

__device__ __forceinline__ double mk_key(float d2, int j) {
    unsigned long long u =
        ((unsigned long long)(unsigned)__float_as_uint(d2) << 32) | (unsigned)j;
    return __longlong_as_double(u);
}

// d2 for a pair of queries vs one point. EXACT op order of prior rounds
// (per-component): cross = (qx*px + qy*py) + qz*pz; d2 = (q2+pw) - 2*cross.
__device__ __forceinline__ v2f dist2_pair(const v2f qx2, const v2f qy2,
                                          const v2f qz2, const v2f q22,
                                          const float4 p) {
    #pragma clang fp contract(off)
    const v2f px = {p.x, p.x};
    const v2f py = {p.y, p.y};
    const v2f pz = {p.z, p.z};
    const v2f pw = {p.w, p.w};
    const v2f t0 = qx2 * px;
    const v2f t1 = qy2 * py;
    const v2f t2 = t0 + t1;
    const v2f t3 = qz2 * pz;
    const v2f cr = t2 + t3;
    const v2f qs = q22 + pw;
    const v2f cc = cr + cr;
    const v2f d2 = qs - cc;
    return d2;
}

// Scalar d2, same exact op order (used by tie-overflow fallback + generic).
__device__ __forceinline__ float dist2_scalar(float qx, float qy, float qz,
                                              float q2, const float4 p) {
    #pragma clang fp contract(off)
    const float t0 = qx * p.x;
    const float t1 = qy * p.y;
    const float t2 = t0 + t1;
    const float t3 = qz * p.z;
    const float cr = t2 + t3;
    const float qs = q2 + p.w;
    const float cc = cr + cr;
    const float d2 = qs - cc;
    return d2;
}

__device__ __forceinline__ bool lex_less(float d, int j, float D, int J) {
    return (d < D) || (d == D && j < J);
}

// ---------------- Split path: kernel 1 — kNN select ----------------
template <int CHUNK>
__global__ __launch_bounds__(512, 4) void fp_knn_select(
    const float* __restrict__ new_xyz,   // [B*M, 3]
    const float4* __restrict__ pts,      // [B*N] packed (x,y,z,s2)
    int4*  __restrict__ jb,              // [B*M] neighbor idx (x,y,z)
    float4* __restrict__ wb,             // [B*M] weights (x,y,z)
    int N, int blocks_per_batch)
{
    __shared__ float s_v[SPLIT][QPB][3];   // 12 KiB pass-1 values
    __shared__ float s_T[QPB];
    __shared__ int   s_cnt[QPB];
    __shared__ float s_sd[QPB][CAP];       // 4 KiB
    __shared__ int   s_sj[QPB][CAP];       // 4 KiB

    int g = blockIdx.x;
    if (gridDim.x == 512 && blocks_per_batch == 128) {
        const int xcd = g & 7, slot = g >> 3;        // slot in [0,64)
        g = (xcd >> 1) * 128 + (xcd & 1) * 64 + slot;
    }

    const int tid  = threadIdx.x;
    const int lane = tid & 63;
    const int b    = g / blocks_per_batch;
    const int src_base = b * N;
    const int m0 = g * QPB + lane;   // query 0 of this lane
    const int m1 = m0 + 64;          // query 1 of this lane

    const float q0x = new_xyz[(size_t)m0 * 3 + 0];
    const float q0y = new_xyz[(size_t)m0 * 3 + 1];
    const float q0z = new_xyz[(size_t)m0 * 3 + 2];
    const float q1x = new_xyz[(size_t)m1 * 3 + 0];
    const float q1y = new_xyz[(size_t)m1 * 3 + 1];
    const float q1z = new_xyz[(size_t)m1 * 3 + 2];
    const float q02 = __fadd_rn(__fadd_rn(__fmul_rn(q0x, q0x), __fmul_rn(q0y, q0y)),
                                __fmul_rn(q0z, q0z));
    const float q12 = __fadd_rn(__fadd_rn(__fmul_rn(q1x, q1x), __fmul_rn(q1y, q1y)),
                                __fmul_rn(q1z, q1z));
    const v2f qx2 = {q0x, q1x};
    const v2f qy2 = {q0y, q1y};
    const v2f qz2 = {q0z, q1z};
    const v2f q22 = {q02, q12};

    const int cw    = tid >> 6;          // wave id 0..7
    const int cbase = cw * CHUNK;
    const float4* __restrict__ cp = pts + src_base + cbase;

    // ---- pass 1: three smallest d2 VALUES per (wave, query) ----
    float va0 = FLT_MAX, va1 = FLT_MAX, va2 = FLT_MAX;
    float vb0 = FLT_MAX, vb1 = FLT_MAX, vb2 = FLT_MAX;
    #pragma unroll 8
    for (int j = 0; j < CHUNK; ++j) {
        const float4 p = cp[j];
        const v2f d2 = dist2_pair(qx2, qy2, qz2, q22, p);
        const float na0 = fminf(d2.x, va0);
        const float na1 = fminf(fmaxf(d2.x, va0), va1);
        const float na2 = fminf(fmaxf(d2.x, va1), va2);
        va0 = na0; va1 = na1; va2 = na2;
        const float nb0 = fminf(d2.y, vb0);
        const float nb1 = fminf(fmaxf(d2.y, vb0), vb1);
        const float nb2 = fminf(fmaxf(d2.y, vb1), vb2);
        vb0 = nb0; vb1 = nb1; vb2 = nb2;
    }
    s_v[cw][lane][0]      = va0; s_v[cw][lane][1]      = va1; s_v[cw][lane][2]      = va2;
    s_v[cw][lane + 64][0] = vb0; s_v[cw][lane + 64][1] = vb1; s_v[cw][lane + 64][2] = vb2;
    __syncthreads();

    // ---- merge: global 3rd-smallest value = threshold T ----
    if (tid < QPB) {
        float m0v = FLT_MAX, m1v = FLT_MAX, m2v = FLT_MAX;
        #pragma unroll
        for (int ss = 0; ss < SPLIT; ++ss) {
            #pragma unroll
            for (int r = 0; r < 3; ++r) {
                const float d = s_v[ss][tid][r];
                const float n0 = fminf(d, m0v);
                const float n1 = fminf(fmaxf(d, m0v), m1v);
                const float n2 = fminf(fmaxf(d, m1v), m2v);
                m0v = n0; m1v = n1; m2v = n2;
            }
        }
        s_T[tid] = m2v;
        s_cnt[tid] = 0;
    }
    __syncthreads();

    // ---- pass 2: rescan, push d2 <= T hits (bit-identical d2) ----
    {
        const float Ta = s_T[lane];
        const float Tb = s_T[lane + 64];
        #pragma unroll 8
        for (int j = 0; j < CHUNK; ++j) {
            const float4 p = cp[j];
            const v2f d2 = dist2_pair(qx2, qy2, qz2, q22, p);
            const bool ha = (d2.x <= Ta);
            const bool hb = (d2.y <= Tb);
            if (__any(ha || hb)) {
                if (ha) {
                    const int slot = atomicAdd(&s_cnt[lane], 1);
                    if (slot < CAP) { s_sd[lane][slot] = d2.x; s_sj[lane][slot] = cbase + j; }
                }
                if (hb) {
                    const int slot = atomicAdd(&s_cnt[lane + 64], 1);
                    if (slot < CAP) { s_sd[lane + 64][slot] = d2.y; s_sj[lane + 64][slot] = cbase + j; }
                }
            }
        }
    }
    __syncthreads();

    // ---- finalize: pick 3 lexicographically smallest (d2, idx), weights ----
    if (tid < QPB) {
        const int q = tid;
        const int cnt = s_cnt[q];
        float bd0 = FLT_MAX, bd1 = FLT_MAX, bd2 = FLT_MAX;
        int   bj0 = 0x7fffffff, bj1 = 0x7fffffff, bj2 = 0x7fffffff;
        if (cnt <= CAP) {
            for (int i = 0; i < cnt; ++i) {
                const float d = s_sd[q][i];
                const int   j = s_sj[q][i];
                if (lex_less(d, j, bd2, bj2)) {
                    if (lex_less(d, j, bd1, bj1)) {
                        bd2 = bd1; bj2 = bj1;
                        if (lex_less(d, j, bd0, bj0)) {
                            bd1 = bd0; bj1 = bj0; bd0 = d; bj0 = j;
                        } else { bd1 = d; bj1 = j; }
                    } else { bd2 = d; bj2 = j; }
                }
            }
        } else {
            // Pathological tie overflow: exact serial rescan of all N points.
            const int mq = g * QPB + q;
            const float qx = new_xyz[(size_t)mq * 3 + 0];
            const float qy = new_xyz[(size_t)mq * 3 + 1];
            const float qz = new_xyz[(size_t)mq * 3 + 2];
            const float q2 = __fadd_rn(
                __fadd_rn(__fmul_rn(qx, qx), __fmul_rn(qy, qy)), __fmul_rn(qz, qz));
            for (int j = 0; j < N; ++j) {
                const float4 p = pts[src_base + j];
                const float d2 = dist2_scalar(qx, qy, qz, q2, p);
                if (lex_less(d2, j, bd2, bj2)) {
                    if (lex_less(d2, j, bd1, bj1)) {
                        bd2 = bd1; bj2 = bj1;
                        if (lex_less(d2, j, bd0, bj0)) {
                            bd1 = bd0; bj1 = bj0; bd0 = d2; bj0 = j;
                        } else { bd1 = d2; bj1 = j; }
                    } else { bd2 = d2; bj2 = j; }
                }
            }
        }
        const float e0 = sqrtf(fmaxf(bd0, 1e-12f));
        const float e1 = sqrtf(fmaxf(bd1, 1e-12f));
        const float e2 = sqrtf(fmaxf(bd2, 1e-12f));
        const float r0 = 1.0f / (e0 + 1e-8f);
        const float r1 = 1.0f / (e1 + 1e-8f);
        const float r2 = 1.0f / (e2 + 1e-8f);
        const float rs = r0 + r1 + r2;
        const int mq = g * QPB + q;
        jb[mq] = make_int4(bj0, bj1, bj2, 0);
        wb[mq] = make_float4(r0 / rs, r1 / rs, r2 / rs, 0.0f);
    }
}

// ---------------- Split path: kernel 2 — gather + blend ----------------
__global__ __launch_bounds__(256, 8) void fp_gather(
    const float4* __restrict__ feat4,    // [B*N, 64]
    const int4*  __restrict__ jb,        // [B*M]
    const float4* __restrict__ wb,       // [B*M]
    float4* __restrict__ out4,           // [B*M, 64]
    int N, int M)
{
    const int tid  = threadIdx.x;
    const int lane = tid & 63;
    const int wv   = tid >> 6;
    const int qblk = blockIdx.x * 16;        // 16 queries per block
    const int b    = qblk / M;               // 16 | M -> uniform per block
    const int src_base = b * N;
    #pragma unroll
    for (int t = 0; t < 4; ++t) {
        const int q = qblk + wv * 4 + t;
        const int4   J = jb[q];
        const float4 W = wb[q];
        const float4 f0 = feat4[(size_t)(src_base + J.x) * 64 + lane];
        const float4 f1 = feat4[(size_t)(src_base + J.y) * 64 + lane];
        const float4 f2 = feat4[(size_t)(src_base + J.z) * 64 + lane];
        const float u0 = W.x, u1 = W.y, u2 = W.z;
        float4 o;
        o.x = u0 * f0.x + u1 * f1.x + u2 * f2.x;
        o.y = u0 * f0.y + u1 * f1.y + u2 * f2.y;
        o.z = u0 * f0.z + u1 * f1.z + u2 * f2.z;
        o.w = u0 * f0.w + u1 * f1.w + u2 * f2.w;
        out4[(size_t)q * 64 + lane] = o;
    }
}

// ---------------- Fused fallback (R8) — used if ws too small ----------------
template <int CHUNK>
__global__ __launch_bounds__(512, 4) void fp_knn_main(
    const float* __restrict__ new_xyz,
    const float4* __restrict__ pts,
    const float4* __restrict__ feat4,
    float4* __restrict__ out4,
    int N, int blocks_per_batch)
{
    __shared__ double s_k[SPLIT][QPB][3];
    __shared__ float  s_w[QPB][3];
    __shared__ int    s_j[QPB][3];

    int g = blockIdx.x;
    if (gridDim.x == 512 && blocks_per_batch == 128) {
        const int xcd = g & 7, slot = g >> 3;
        g = (xcd >> 1) * 128 + (xcd & 1) * 64 + slot;
    }

    const int tid  = threadIdx.x;
    const int lane = tid & 63;
    const int b    = g / blocks_per_batch;
    const int src_base = b * N;
    const int m0 = g * QPB + lane;
    const int m1 = m0 + 64;

    const float q0x = new_xyz[(size_t)m0 * 3 + 0];
    const float q0y = new_xyz[(size_t)m0 * 3 + 1];
    const float q0z = new_xyz[(size_t)m0 * 3 + 2];
    const float q1x = new_xyz[(size_t)m1 * 3 + 0];
    const float q1y = new_xyz[(size_t)m1 * 3 + 1];
    const float q1z = new_xyz[(size_t)m1 * 3 + 2];
    const float q02 = __fadd_rn(__fadd_rn(__fmul_rn(q0x, q0x), __fmul_rn(q0y, q0y)),
                                __fmul_rn(q0z, q0z));
    const float q12 = __fadd_rn(__fadd_rn(__fmul_rn(q1x, q1x), __fmul_rn(q1y, q1y)),
                                __fmul_rn(q1z, q1z));
    const v2f qx2 = {q0x, q1x};
    const v2f qy2 = {q0y, q1y};
    const v2f qz2 = {q0z, q1z};
    const v2f q22 = {q02, q12};

    const int cw    = tid >> 6;
    const int cbase = cw * CHUNK;
    const float4* __restrict__ cp = pts + src_base + cbase;

    double k00 = __longlong_as_double(KEY_INIT);
    double k01 = k00, k02 = k00;
    double k10 = k00, k11 = k00, k12 = k00;

    #pragma unroll 8
    for (int j = 0; j < CHUNK; ++j) {
        const float4 p = cp[j];
        const v2f d2 = dist2_pair(qx2, qy2, qz2, q22, p);
        const double ka = mk_key(d2.x, cbase + j);
        const double kb = mk_key(d2.y, cbase + j);
        const double a0 = fmin(ka, k00);
        const double a1 = fmin(fmax(ka, k00), k01);
        const double a2 = fmin(fmax(ka, k01), k02);
        k00 = a0; k01 = a1; k02 = a2;
        const double b0 = fmin(kb, k10);
        const double b1 = fmin(fmax(kb, k10), k11);
        const double b2 = fmin(fmax(kb, k11), k12);
        k10 = b0; k11 = b1; k12 = b2;
    }

    s_k[cw][lane][0]      = k00; s_k[cw][lane][1]      = k01; s_k[cw][lane][2]      = k02;
    s_k[cw][lane + 64][0] = k10; s_k[cw][lane + 64][1] = k11; s_k[cw][lane + 64][2] = k12;
    __syncthreads();

    if (tid < QPB) {
        double m0k = __longlong_as_double(KEY_INIT), m1k = m0k, m2k = m0k;
        #pragma unroll
        for (int ss = 0; ss < SPLIT; ++ss) {
            #pragma unroll
            for (int r = 0; r < 3; ++r) {
                const double d = s_k[ss][tid][r];
                const double n0 = fmin(d, m0k);
                const double n1 = fmin(fmax(d, m0k), m1k);
                const double n2 = fmin(fmax(d, m1k), m2k);
                m0k = n0; m1k = n1; m2k = n2;
            }
        }
        unsigned long long u0 = __double_as_longlong(m0k);
        unsigned long long u1 = __double_as_longlong(m1k);
        unsigned long long u2 = __double_as_longlong(m2k);
        const float d0 = __uint_as_float((unsigned)(u0 >> 32));
        const float d1 = __uint_as_float((unsigned)(u1 >> 32));
        const float d2 = __uint_as_float((unsigned)(u2 >> 32));
        const float e0 = sqrtf(fmaxf(d0, 1e-12f));
        const float e1 = sqrtf(fmaxf(d1, 1e-12f));
        const float e2 = sqrtf(fmaxf(d2, 1e-12f));
        const float r0 = 1.0f / (e0 + 1e-8f);
        const float r1 = 1.0f / (e1 + 1e-8f);
        const float r2 = 1.0f / (e2 + 1e-8f);
        const float rs = r0 + r1 + r2;
        s_w[tid][0] = r0 / rs; s_w[tid][1] = r1 / rs; s_w[tid][2] = r2 / rs;
        s_j[tid][0] = (int)(u0 & 0xffffffffu);
        s_j[tid][1] = (int)(u1 & 0xffffffffu);
        s_j[tid][2] = (int)(u2 & 0xffffffffu);
    }
    __syncthreads();

    const int wv    = tid >> 6;
    const int qbase = g * QPB;
    #pragma unroll 4
    for (int t = 0; t < QPB / SPLIT; ++t) {
        const int qq = wv * (QPB / SPLIT) + t;
        const int   a0 = s_j[qq][0], a1 = s_j[qq][1], a2 = s_j[qq][2];
        const float u0 = s_w[qq][0], u1 = s_w[qq][1], u2 = s_w[qq][2];
        const float4 f0 = feat4[(size_t)(src_base + a0) * 64 + lane];
        const float4 f1 = feat4[(size_t)(src_base + a1) * 64 + lane];
        const float4 f2 = feat4[(size_t)(src_base + a2) * 64 + lane];
        float4 o;
        o.x = u0 * f0.x + u1 * f1.x + u2 * f2.x;
        o.y = u0 * f0.y + u1 * f1.y + u2 * f2.y;
        o.z = u0 * f0.z + u1 * f1.z + u2 * f2.z;
        o.w = u0 * f0.w + u1 * f1.w + u2 * f2.w;
        out4[(size_t)(qbase + qq) * 64 + lane] = o;
    }
}

// Generic fallback (shape mismatch only) — same semantics, unoptimized.
__global__ void fp_knn_generic(
    const float* __restrict__ new_xyz, const float* __restrict__ xyz,
    const float* __restrict__ feat, float* __restrict__ out,
    int N, int M, int Btot)
{
    const int m = blockIdx.x * blockDim.x + threadIdx.x;
    if (m >= Btot * M) return;
    const int b = m / M;
    const int src_base = b * N;
    const float qx = new_xyz[(size_t)m * 3 + 0];
    const float qy = new_xyz[(size_t)m * 3 + 1];
    const float qz = new_xyz[(size_t)m * 3 + 2];
    const float q2 = __fadd_rn(__fadd_rn(__fmul_rn(qx, qx), __fmul_rn(qy, qy)),
                               __fmul_rn(qz, qz));
    double k0 = __longlong_as_double(KEY_INIT), k1 = k0, k2 = k0;
    for (int j = 0; j < N; ++j) {
        const float sx = xyz[(size_t)(src_base + j) * 3 + 0];
        const float sy = xyz[(size_t)(src_base + j) * 3 + 1];
        const float sz = xyz[(size_t)(src_base + j) * 3 + 2];
        const float s2 = __fadd_rn(__fadd_rn(__fmul_rn(sx, sx), __fmul_rn(sy, sy)),
                                   __fmul_rn(sz, sz));
        const float4 p = make_float4(sx, sy, sz, s2);
        const float d2 = dist2_scalar(qx, qy, qz, q2, p);
        const double key = mk_key(d2, j);
        const double n0 = fmin(key, k0);
        const double n1 = fmin(fmax(key, k0), k1);
        const double n2 = fmin(fmax(key, k1), k2);
        k0 = n0; k1 = n1; k2 = n2;
    }
    unsigned long long u0 = __double_as_longlong(k0);
    unsigned long long u1 = __double_as_longlong(k1);
    unsigned long long u2 = __double_as_longlong(k2);
    const float e0 = sqrtf(fmaxf(__uint_as_float((unsigned)(u0 >> 32)), 1e-12f));
    const float e1 = sqrtf(fmaxf(__uint_as_float((unsigned)(u1 >> 32)), 1e-12f));
    const float e2 = sqrtf(fmaxf(__uint_as_float((unsigned)(u2 >> 32)), 1e-12f));
    const float r0 = 1.0f / (e0 + 1e-8f);
    const float r1 = 1.0f / (e1 + 1e-8f);
    const float r2 = 1.0f / (e2 + 1e-8f);
    const float rs = r0 + r1 + r2;
    const float w0 = r0 / rs, w1 = r1 / rs, w2 = r2 / rs;
    const int a0 = (int)(u0 & 0xffffffffu), a1 = (int)(u1 & 0xffffffffu),
              a2 = (int)(u2 & 0xffffffffu);
    const int C = 256;
    for (int c = 0; c < C; ++c) {
        out[(size_t)m * C + c] =
            w0 * feat[(size_t)(src_base + a0) * C + c] +
            w1 * feat[(size_t)(src_base + a1) * C + c] +
            w2 * feat[(size_t)(src_base + a2) * C + c];
    }
}

extern "C" void kernel_launch(void* const* d_in, const int* in_sizes, int n_in,
                              void* d_out, int out_size, void* d_ws, size_t ws_size,
                              hipStream_t stream) {
    const float* xyz     = (const float*)d_in[0];
    const float* new_xyz = (const float*)d_in[1];
    const float* feat    = (const float*)d_in[2];
    float* out = (float*)d_out;

    const int B = in_sizes[3];                 // 4
    const int N = in_sizes[0] / (3 * B);       // 4096
    const int M = in_sizes[1] / (3 * B);       // 16384

    const int Q = B * M;                       // 65536
    const size_t pts_bytes = (size_t)(B * N) * sizeof(float4);   // 256 KiB
    const size_t jb_bytes  = (size_t)Q * sizeof(int4);           // 1 MiB
    const size_t wb_bytes  = (size_t)Q * sizeof(float4);         // 1 MiB
    const size_t need_split = pts_bytes + jb_bytes + wb_bytes;   // 2.25 MiB

    const bool shape_ok = (N % SPLIT == 0) && (N / SPLIT == 512) &&
                          (M % QPB == 0) && (M % 16 == 0);
    if (shape_ok && ws_size >= need_split) {
        float4* pts = (float4*)d_ws;
        int4*   jb  = (int4*)((char*)d_ws + pts_bytes);
        float4* wb  = (float4*)((char*)d_ws + pts_bytes + jb_bytes);
        pack_pts<<<(B * N + 255) / 256, 256, 0, stream>>>(xyz, pts, B * N);
        const int blocks = Q / QPB;            // 512
        fp_knn_select<512><<<blocks, 512, 0, stream>>>(
            new_xyz, pts, jb, wb, N, M / QPB);
        fp_gather<<<Q / 16, 256, 0, stream>>>(
            (const float4*)feat, jb, wb, (float4*)out, N, M);
    } else if (shape_ok && ws_size >= pts_bytes) {
        pack_pts<<<(B * N + 255) / 256, 256, 0, stream>>>(xyz, (float4*)d_ws, B * N);
        const int blocks = Q / QPB;            // 512
        fp_knn_main<512><<<blocks, 512, 0, stream>>>(
            new_xyz, (const float4*)d_ws, (const float4*)feat, (float4*)out,
            N, M / QPB);
    } else {
        fp_knn_generic<<<(Q + 255) / 256, 256, 0, stream>>>(
            new_xyz, xyz, feat, out, N, M, B);
    }
}

// Round 6
// 207.599 us; speedup vs baseline: 1.3345x; 1.3345x over previous
//
#include <hip/hip_runtime.h>
#include <float.h>

// FeatPropagation k=3 NN interpolation, round 10.
// R9 post-mortem (split kernels, 2-pass f32): fp_knn_select ALONE = 189us >
// whole fused f64 kernel (146us). Two f32 passes cost ~111us busy => f64
// min/max is ~half-rate (4cyc) not quarter-rate; the 5-op f64 key network is
// the cheapest exact selection (f32 cmp/cndmask net = 15 instr > f64 5).
// 2-pass REVERTED. Surviving invariant across R5-R9: stall ~30-40% always
// co-occurs with VGPR_Count 24-56 -- the compiler SINKS point-stream loads to
// just-before-use, collapsing every hand-written prefetch (R7 scratch, R8
// resched). R10 = R8 fused structure + __builtin_amdgcn_sched_barrier(0)
// fences around load/process clusters: sinking becomes illegal, banks must
// live in regs. VERIFY: VGPR_Count ~100-128 (if still ~56 -> fence failed ->
// pivot to grid pruning next round).
//
// PROTECTED (absmax 0.015625, 4.7x under threshold): d2 computed as
// (q2+s2) - 2*((qx*sx+qy*sy)+qz*sz) with per-op f32 rounding (contract off,
// no fma, no reassociation) in this exact order; strict < via packed (d2,idx)
// f64 key min; ties -> lower index. Do NOT switch to fma/dx^2 form.

#define QPL   2     // queries per lane
#define QPB   128   // queries per block = 64 * QPL
#define SPLIT 8     // candidate chunks per block == waves per block
#define KEY_INIT 0x7FEFFFFFFFFFFFFFULL  // > any real packed key

typedef float v2f __attribute__((ext_vector_type(2)));

__global__ void pack_pts(const float* __restrict__ xyz,
                         float4* __restrict__ pts, int total) {
    int i = blockIdx.x * blockDim.x + threadIdx.x;
    if (i < total) {
        const float sx = xyz[(size_t)i * 3 + 0];
        const float sy = xyz[(size_t)i * 3 + 1];
        const float sz = xyz[(size_t)i * 3 + 2];
        const float s2 = __fadd_rn(__fadd_rn(__fmul_rn(sx, sx), __fmul_rn(sy, sy)),
                                   __fmul_rn(sz, sz));
        pts[i] = make_float4(sx, sy, sz, s2);
    }
}

__device__ __forceinline__ double mk_key(float d2, int j) {
    unsigned long long u =
        ((unsigned long long)(unsigned)__float_as_uint(d2) << 32) | (unsigned)j;
    return __longlong_as_double(u);
}

// d2 for a pair of queries vs one point. EXACT op order of prior rounds
// (per-component): cross = (qx*px + qy*py) + qz*pz; d2 = (q2+pw) - 2*cross.
__device__ __forceinline__ v2f dist2_pair(const v2f qx2, const v2f qy2,
                                          const v2f qz2, const v2f q22,
                                          const float4 p) {
    #pragma clang fp contract(off)
    const v2f px = {p.x, p.x};
    const v2f py = {p.y, p.y};
    const v2f pz = {p.z, p.z};
    const v2f pw = {p.w, p.w};
    const v2f t0 = qx2 * px;
    const v2f t1 = qy2 * py;
    const v2f t2 = t0 + t1;
    const v2f t3 = qz2 * pz;
    const v2f cr = t2 + t3;
    const v2f qs = q22 + pw;
    const v2f cc = cr + cr;
    const v2f d2 = qs - cc;
    return d2;
}

// Scalar d2, same exact op order (generic fallback).
__device__ __forceinline__ float dist2_scalar(float qx, float qy, float qz,
                                              float q2, const float4 p) {
    #pragma clang fp contract(off)
    const float t0 = qx * p.x;
    const float t1 = qy * p.y;
    const float t2 = t0 + t1;
    const float t3 = qz * p.z;
    const float cr = t2 + t3;
    const float qs = q2 + p.w;
    const float cc = cr + cr;
    const float d2 = qs - cc;
    return d2;
}

template <int CHUNK>
__global__ __launch_bounds__(512, 4) void fp_knn_main(
    const float* __restrict__ new_xyz,   // [B*M, 3]
    const float4* __restrict__ pts,      // [B*N] packed (x,y,z,s2)
    const float4* __restrict__ feat4,    // [B*N, 64]  (C=256)
    float4* __restrict__ out4,           // [B*M, 64]
    int N, int blocks_per_batch)
{
    __shared__ double s_k[SPLIT][QPB][3];   // 24 KiB
    __shared__ float  s_w[QPB][3];
    __shared__ int    s_j[QPB][3];

    int g = blockIdx.x;
    // XCD swizzle (bijective, grid 512): batch b's 128 blocks -> XCDs {2b,2b+1}
    // so its 4 MiB feat slab stays in one XCD pair's L2.
    if (gridDim.x == 512 && blocks_per_batch == 128) {
        const int xcd = g & 7, slot = g >> 3;        // slot in [0,64)
        g = (xcd >> 1) * 128 + (xcd & 1) * 64 + slot;
    }

    const int tid  = threadIdx.x;
    const int lane = tid & 63;
    const int b    = g / blocks_per_batch;
    const int src_base = b * N;
    const int m0 = g * QPB + lane;   // query 0 of this lane
    const int m1 = m0 + 64;          // query 1 of this lane

    const float q0x = new_xyz[(size_t)m0 * 3 + 0];
    const float q0y = new_xyz[(size_t)m0 * 3 + 1];
    const float q0z = new_xyz[(size_t)m0 * 3 + 2];
    const float q1x = new_xyz[(size_t)m1 * 3 + 0];
    const float q1y = new_xyz[(size_t)m1 * 3 + 1];
    const float q1z = new_xyz[(size_t)m1 * 3 + 2];
    const float q02 = __fadd_rn(__fadd_rn(__fmul_rn(q0x, q0x), __fmul_rn(q0y, q0y)),
                                __fmul_rn(q0z, q0z));
    const float q12 = __fadd_rn(__fadd_rn(__fmul_rn(q1x, q1x), __fmul_rn(q1y, q1y)),
                                __fmul_rn(q1z, q1z));
    const v2f qx2 = {q0x, q1x};
    const v2f qy2 = {q0y, q1y};
    const v2f qz2 = {q0z, q1z};
    const v2f q22 = {q02, q12};

    // Per-wave chunk; per-lane broadcast VMEM (64 identical addrs -> one
    // request; vmcnt counted+in-order).
    const int cw    = tid >> 6;          // 0..7
    const int cbase = cw * CHUNK;
    const float4* __restrict__ cp = pts + src_base + cbase;

    double k00 = __longlong_as_double(KEY_INIT);
    double k01 = k00, k02 = k00;
    double k10 = k00, k11 = k00, k12 = k00;

    constexpr int G  = 8;
    constexpr int NG = CHUNK / G;        // 64 groups (even)

    // Explicit register banks: touched ONLY with compile-time indices.
    float4 A[G], B[G];

    auto process = [&](const float4 p, int cj) {
        const v2f d2 = dist2_pair(qx2, qy2, qz2, q22, p);
        const double ka = mk_key(d2.x, cj);
        const double kb = mk_key(d2.y, cj);
        const double a0 = fmin(ka, k00);
        const double a1 = fmin(fmax(ka, k00), k01);
        const double a2 = fmin(fmax(ka, k01), k02);
        k00 = a0; k01 = a1; k02 = a2;
        const double b0 = fmin(kb, k10);
        const double b1 = fmin(fmax(kb, k10), k11);
        const double b2 = fmin(fmax(kb, k11), k12);
        k10 = b0; k11 = b1; k12 = b2;
    };

    // Prologue: bank A <- group 0.
    #pragma unroll
    for (int t = 0; t < G; ++t) A[t] = cp[t];
    __builtin_amdgcn_sched_barrier(0);

    // Ping-pong main loop. sched_barrier(0) after each cluster forbids the
    // scheduler from sinking prefetch loads into the compute cluster (the
    // collapse that produced VGPR=24/48/56 in R5/R7/R8).
    int gi = 0;
    for (; gi < NG - 2; gi += 2) {
        const float4* nx1 = cp + (gi + 1) * G;
        #pragma unroll
        for (int t = 0; t < G; ++t) B[t] = nx1[t];
        __builtin_amdgcn_sched_barrier(0);
        #pragma unroll
        for (int t = 0; t < G; ++t) process(A[t], cbase + gi * G + t);
        __builtin_amdgcn_sched_barrier(0);
        const float4* nx2 = cp + (gi + 2) * G;
        #pragma unroll
        for (int t = 0; t < G; ++t) A[t] = nx2[t];
        __builtin_amdgcn_sched_barrier(0);
        #pragma unroll
        for (int t = 0; t < G; ++t) process(B[t], cbase + (gi + 1) * G + t);
        __builtin_amdgcn_sched_barrier(0);
    }
    // Tail: gi == NG-2.
    {
        const float4* nx1 = cp + (gi + 1) * G;
        #pragma unroll
        for (int t = 0; t < G; ++t) B[t] = nx1[t];
        __builtin_amdgcn_sched_barrier(0);
        #pragma unroll
        for (int t = 0; t < G; ++t) process(A[t], cbase + gi * G + t);
        #pragma unroll
        for (int t = 0; t < G; ++t) process(B[t], cbase + (gi + 1) * G + t);
    }

    s_k[cw][lane][0]      = k00; s_k[cw][lane][1]      = k01; s_k[cw][lane][2]      = k02;
    s_k[cw][lane + 64][0] = k10; s_k[cw][lane + 64][1] = k11; s_k[cw][lane + 64][2] = k12;
    __syncthreads();

    // ---- 24-way merge per query on packed keys (2 waves, tie-exact) ----
    if (tid < QPB) {
        double m0k = __longlong_as_double(KEY_INIT), m1k = m0k, m2k = m0k;
        #pragma unroll
        for (int ss = 0; ss < SPLIT; ++ss) {
            #pragma unroll
            for (int r = 0; r < 3; ++r) {
                const double d = s_k[ss][tid][r];
                const double n0 = fmin(d, m0k);
                const double n1 = fmin(fmax(d, m0k), m1k);
                const double n2 = fmin(fmax(d, m1k), m2k);
                m0k = n0; m1k = n1; m2k = n2;
            }
        }
        unsigned long long u0 = __double_as_longlong(m0k);
        unsigned long long u1 = __double_as_longlong(m1k);
        unsigned long long u2 = __double_as_longlong(m2k);
        const float d0 = __uint_as_float((unsigned)(u0 >> 32));
        const float d1 = __uint_as_float((unsigned)(u1 >> 32));
        const float d2 = __uint_as_float((unsigned)(u2 >> 32));
        const float e0 = sqrtf(fmaxf(d0, 1e-12f));
        const float e1 = sqrtf(fmaxf(d1, 1e-12f));
        const float e2 = sqrtf(fmaxf(d2, 1e-12f));
        const float r0 = 1.0f / (e0 + 1e-8f);
        const float r1 = 1.0f / (e1 + 1e-8f);
        const float r2 = 1.0f / (e2 + 1e-8f);
        const float rs = r0 + r1 + r2;
        s_w[tid][0] = r0 / rs; s_w[tid][1] = r1 / rs; s_w[tid][2] = r2 / rs;
        s_j[tid][0] = (int)(u0 & 0xffffffffu);
        s_j[tid][1] = (int)(u1 & 0xffffffffu);
        s_j[tid][2] = (int)(u2 & 0xffffffffu);
    }
    __syncthreads();

    // ---- phase B: gather + interpolate; each of 8 waves handles 16 queries ----
    const int wv    = tid >> 6;
    const int qbase = g * QPB;
    #pragma unroll 4
    for (int t = 0; t < QPB / SPLIT; ++t) {
        const int qq = wv * (QPB / SPLIT) + t;
        const int   a0 = s_j[qq][0], a1 = s_j[qq][1], a2 = s_j[qq][2];
        const float u0 = s_w[qq][0], u1 = s_w[qq][1], u2 = s_w[qq][2];
        const float4 f0 = feat4[(size_t)(src_base + a0) * 64 + lane];
        const float4 f1 = feat4[(size_t)(src_base + a1) * 64 + lane];
        const float4 f2 = feat4[(size_t)(src_base + a2) * 64 + lane];
        float4 o;
        o.x = u0 * f0.x + u1 * f1.x + u2 * f2.x;
        o.y = u0 * f0.y + u1 * f1.y + u2 * f2.y;
        o.z = u0 * f0.z + u1 * f1.z + u2 * f2.z;
        o.w = u0 * f0.w + u1 * f1.w + u2 * f2.w;
        out4[(size_t)(qbase + qq) * 64 + lane] = o;
    }
}

// Generic fallback (shape mismatch only) — same semantics, unoptimized.
__global__ void fp_knn_generic(
    const float* __restrict__ new_xyz, const float* __restrict__ xyz,
    const float* __restrict__ feat, float* __restrict__ out,
    int N, int M, int Btot)
{
    const int m = blockIdx.x * blockDim.x + threadIdx.x;
    if (m >= Btot * M) return;
    const int b = m / M;
    const int src_base = b * N;
    const float qx = new_xyz[(size_t)m * 3 + 0];
    const float qy = new_xyz[(size_t)m * 3 + 1];
    const float qz = new_xyz[(size_t)m * 3 + 2];
    const float q2 = __fadd_rn(__fadd_rn(__fmul_rn(qx, qx), __fmul_rn(qy, qy)),
                               __fmul_rn(qz, qz));
    double k0 = __longlong_as_double(KEY_INIT), k1 = k0, k2 = k0;
    for (int j = 0; j < N; ++j) {
        const float sx = xyz[(size_t)(src_base + j) * 3 + 0];
        const float sy = xyz[(size_t)(src_base + j) * 3 + 1];
        const float sz = xyz[(size_t)(src_base + j) * 3 + 2];
        const float s2 = __fadd_rn(__fadd_rn(__fmul_rn(sx, sx), __fmul_rn(sy, sy)),
                                   __fmul_rn(sz, sz));
        const float4 p = make_float4(sx, sy, sz, s2);
        const float d2 = dist2_scalar(qx, qy, qz, q2, p);
        const double key = mk_key(d2, j);
        const double n0 = fmin(key, k0);
        const double n1 = fmin(fmax(key, k0), k1);
        const double n2 = fmin(fmax(key, k1), k2);
        k0 = n0; k1 = n1; k2 = n2;
    }
    unsigned long long u0 = __double_as_longlong(k0);
    unsigned long long u1 = __double_as_longlong(k1);
    unsigned long long u2 = __double_as_longlong(k2);
    const float e0 = sqrtf(fmaxf(__uint_as_float((unsigned)(u0 >> 32)), 1e-12f));
    const float e1 = sqrtf(fmaxf(__uint_as_float((unsigned)(u1 >> 32)), 1e-12f));
    const float e2 = sqrtf(fmaxf(__uint_as_float((unsigned)(u2 >> 32)), 1e-12f));
    const float r0 = 1.0f / (e0 + 1e-8f);
    const float r1 = 1.0f / (e1 + 1e-8f);
    const float r2 = 1.0f / (e2 + 1e-8f);
    const float rs = r0 + r1 + r2;
    const float w0 = r0 / rs, w1 = r1 / rs, w2 = r2 / rs;
    const int a0 = (int)(u0 & 0xffffffffu), a1 = (int)(u1 & 0xffffffffu),
              a2 = (int)(u2 & 0xffffffffu);
    const int C = 256;
    for (int c = 0; c < C; ++c) {
        out[(size_t)m * C + c] =
            w0 * feat[(size_t)(src_base + a0) * C + c] +
            w1 * feat[(size_t)(src_base + a1) * C + c] +
            w2 * feat[(size_t)(src_base + a2) * C + c];
    }
}

extern "C" void kernel_launch(void* const* d_in, const int* in_sizes, int n_in,
                              void* d_out, int out_size, void* d_ws, size_t ws_size,
                              hipStream_t stream) {
    const float* xyz     = (const float*)d_in[0];
    const float* new_xyz = (const float*)d_in[1];
    const float* feat    = (const float*)d_in[2];
    float* out = (float*)d_out;

    const int B = in_sizes[3];                 // 4
    const int N = in_sizes[0] / (3 * B);       // 4096
    const int M = in_sizes[1] / (3 * B);       // 16384

    const size_t need = (size_t)(B * N) * sizeof(float4);  // 256 KiB
    const bool fast = (N % SPLIT == 0) && (N / SPLIT == 512) &&
                      (M % QPB == 0) && (ws_size >= need);
    if (fast) {
        pack_pts<<<(B * N + 255) / 256, 256, 0, stream>>>(xyz, (float4*)d_ws, B * N);
        const int blocks = (B * M) / QPB;      // 512
        fp_knn_main<512><<<blocks, 512, 0, stream>>>(
            new_xyz, (const float4*)d_ws, (const float4*)feat, (float4*)out,
            N, M / QPB);
    } else {
        fp_knn_generic<<<(B * M + 255) / 256, 256, 0, stream>>>(
            new_xyz, xyz, feat, out, N, M, B);
    }
}